// Round 1
// baseline (4997.662 us; speedup 1.0000x reference)
//
#include <hip/hip_runtime.h>
#include <math.h>

#define BB 512   // batch
#define TT 2048  // timesteps
#define DD 64    // input dim
#define HH 66    // hidden
#define GG 264   // 4*HH gates

__device__ __forceinline__ float fast_sigmoid(float x) {
  float e = __expf(-x);
  return __fdividef(1.0f, 1.0f + e);
}

__device__ __forceinline__ float fast_tanh(float x) {
  // tanh(x) = 1 - 2/(exp(2x)+1); correct limits at +/-inf
  float e = __expf(2.0f * x);
  return 1.0f - __fdividef(2.0f, e + 1.0f);
}

// One block per batch element. Threads 0..263 each own one gate row
// (W_ih row in 64 VGPRs, W_hh row in 66+2 VGPRs). h broadcast via LDS.
// Wave 4 (tid 256..319) prefetches x_{t+2} at distance 2.
__global__ __launch_bounds__(320, 3) void lstm_seq(
    const float* __restrict__ x,      // [B,T,D]
    const float* __restrict__ W_ih,   // [264,64]
    const float* __restrict__ W_hh,   // [264,66]
    const float* __restrict__ b_ih,   // [264]
    const float* __restrict__ b_hh,   // [264]
    float* __restrict__ hT)           // [66,512] feature-major (workspace)
{
  __shared__ __align__(16) float sx[2][DD];  // double-buffered x_t
  __shared__ __align__(16) float sh[68];     // h (padded, [66..67]=0)
  __shared__ float sact[GG];                 // activated gates

  const int b = blockIdx.x;
  const int tid = threadIdx.x;
  const float* xrow = x + (size_t)b * (TT * DD);

  float wih[DD];
  float whh[68];
  float bias = 0.0f;
  const bool gate = (tid < GG);
  if (gate) {
    const float* wp = W_ih + tid * DD;
#pragma unroll
    for (int k = 0; k < DD; ++k) wih[k] = wp[k];
    const float* hp = W_hh + tid * HH;
#pragma unroll
    for (int k = 0; k < HH; ++k) whh[k] = hp[k];
    whh[66] = 0.0f;
    whh[67] = 0.0f;
    bias = b_ih[tid] + b_hh[tid];
  }
  const int q = tid / HH;          // 0:i 1:f 2:g(cell) 3:o
  const bool istanh = (q == 2);

  if (tid < 68) sh[tid] = 0.0f;    // h0 = 0 (incl. pad)

  float c = 0.0f, h = 0.0f;
  float xcur = 0.0f;
  const int lane = tid - 256;
  if (tid >= 256) {
    sx[0][lane] = xrow[lane];      // x_0 -> buf0
    xcur = xrow[DD + lane];        // x_1 pending in reg
  }
  __syncthreads();                 // barrier A (t=0)

  for (int t = 0; t < TT; ++t) {
    // prefetch: load x_{t+2} to reg, commit x_{t+1} (loaded last iter) to LDS
    if (tid >= 256) {
      int tn = (t + 2 < TT) ? (t + 2) : (TT - 1);
      float nxt = xrow[tn * DD + lane];
      sx[(t + 1) & 1][lane] = xcur;
      xcur = nxt;
    }
    if (gate) {
      const float4* xv = (const float4*)sx[t & 1];
      const float4* hv = (const float4*)sh;
      float a0 = bias, a1 = 0.0f, a2 = 0.0f, a3 = 0.0f;
#pragma unroll
      for (int k = 0; k < 16; ++k) {  // x-projection, 64 MACs
        float4 v = xv[k];
        a0 = fmaf(v.x, wih[4 * k + 0], a0);
        a1 = fmaf(v.y, wih[4 * k + 1], a1);
        a2 = fmaf(v.z, wih[4 * k + 2], a2);
        a3 = fmaf(v.w, wih[4 * k + 3], a3);
      }
#pragma unroll
      for (int k = 0; k < 17; ++k) {  // recurrent part, 68 MACs (2 pad)
        float4 v = hv[k];
        a0 = fmaf(v.x, whh[4 * k + 0], a0);
        a1 = fmaf(v.y, whh[4 * k + 1], a1);
        a2 = fmaf(v.z, whh[4 * k + 2], a2);
        a3 = fmaf(v.w, whh[4 * k + 3], a3);
      }
      float pre = (a0 + a1) + (a2 + a3);
      sact[tid] = istanh ? fast_tanh(pre) : fast_sigmoid(pre);
    }
    __syncthreads();               // barrier B: gates ready
    if (tid < HH) {
      float iv = sact[tid];
      float fv = sact[HH + tid];
      float gv = sact[2 * HH + tid];
      float ov = sact[3 * HH + tid];
      c = fmaf(fv, c, iv * gv);
      h = ov * fast_tanh(c);
      sh[tid] = h;
    }
    __syncthreads();               // barrier A (next step): h ready
  }

  if (tid < HH) hT[tid * BB + b] = h;   // feature-major for coalesced BN
}

// Single block: BN batch-stats per feature (shfl reduce over B=512),
// folded into the final linear layer.
__global__ __launch_bounds__(512) void bn_fc(
    const float* __restrict__ hT,     // [66,512]
    const float* __restrict__ gamma,  // [66]
    const float* __restrict__ beta,   // [66]
    const float* __restrict__ fc_w,   // [66]
    const float* __restrict__ fc_b,   // [1]
    float* __restrict__ out)          // [512]
{
  __shared__ float w2[HH];  // scale_j * fc_w_j
  __shared__ float s2[HH];  // shift_j * fc_w_j
  const int tid = threadIdx.x;
  const int wv = tid >> 6;
  const int lane = tid & 63;

  for (int j = wv; j < HH; j += 8) {
    const float* p = hT + j * BB;
    float s = 0.0f, ss = 0.0f;
#pragma unroll
    for (int m = 0; m < 8; ++m) {
      float v = p[lane + (m << 6)];
      s += v;
      ss = fmaf(v, v, ss);
    }
#pragma unroll
    for (int d = 32; d >= 1; d >>= 1) {
      s += __shfl_xor(s, d);
      ss += __shfl_xor(ss, d);
    }
    if (lane == 0) {
      float mean = s * (1.0f / BB);
      float var = ss * (1.0f / BB) - mean * mean;  // biased, as reference
      float scale = gamma[j] * rsqrtf(var + 1e-5f);
      float shift = beta[j] - mean * scale;
      float fw = fc_w[j];
      w2[j] = scale * fw;
      s2[j] = shift * fw;
    }
  }
  __syncthreads();

  const int bidx = tid;  // 512 threads = 512 batch rows
  float acc = 0.0f;
#pragma unroll
  for (int j = 0; j < HH; ++j)
    acc = fmaf(hT[j * BB + bidx], w2[j], acc);  // coalesced across bidx
  float cst = fc_b[0];
#pragma unroll
  for (int j = 0; j < HH; ++j) cst += s2[j];
  out[bidx] = acc + cst;
}

extern "C" void kernel_launch(void* const* d_in, const int* in_sizes, int n_in,
                              void* d_out, int out_size, void* d_ws, size_t ws_size,
                              hipStream_t stream) {
  const float* x     = (const float*)d_in[0];
  const float* W_ih  = (const float*)d_in[1];
  const float* W_hh  = (const float*)d_in[2];
  const float* b_ih  = (const float*)d_in[3];
  const float* b_hh  = (const float*)d_in[4];
  const float* gamma = (const float*)d_in[5];
  const float* beta  = (const float*)d_in[6];
  const float* fc_w  = (const float*)d_in[7];
  const float* fc_b  = (const float*)d_in[8];
  float* out = (float*)d_out;
  float* hT  = (float*)d_ws;  // 66*512 floats = 135 KB

  lstm_seq<<<BB, 320, 0, stream>>>(x, W_ih, W_hh, b_ih, b_hh, hT);
  bn_fc<<<1, 512, 0, stream>>>(hT, gamma, beta, fc_w, fc_b, out);
}

// Round 2
// 4178.973 us; speedup vs baseline: 1.1959x; 1.1959x over previous
//
#include <hip/hip_runtime.h>
#include <math.h>

#define BB 512   // batch
#define TT 2048  // timesteps
#define DD 64    // input dim
#define HH 66    // hidden
#define GG 264   // 4*HH gates
#define GP 272   // padded gates (17 mfma n-tiles of 16)
#define NTILE 17
#define XSS 68   // xstage row stride (floats) - bank-friendly
#define NSUB 128 // 128 subchunks x 16 steps = 2048

typedef __attribute__((ext_vector_type(8))) __bf16 bf8_t;
typedef __attribute__((ext_vector_type(8))) unsigned short us8_t;
typedef __attribute__((ext_vector_type(4))) float f4_t;

__device__ __forceinline__ float fast_sigmoid(float x) {
  float e = __expf(-x);
  return __fdividef(1.0f, 1.0f + e);
}
__device__ __forceinline__ float fast_tanh(float x) {
  float e = __expf(2.0f * x);
  return 1.0f - __fdividef(2.0f, e + 1.0f);
}
__device__ __forceinline__ unsigned short f2bf(float f) {
  unsigned u = __builtin_bit_cast(unsigned, f);
  unsigned r = (u + 0x7fffu + ((u >> 16) & 1u)) >> 16;
  return (unsigned short)r;
}
__device__ __forceinline__ float bf2f(unsigned short h) {
  unsigned u = ((unsigned)h) << 16;
  return __builtin_bit_cast(float, u);
}
static __device__ __forceinline__ bf8_t as_bf8(us8_t u) {
  union { us8_t u; bf8_t b; } v; v.u = u; return v.b;
}
__device__ __forceinline__ void pack_hilo(float4 p0, float4 p1, us8_t& hi, us8_t& lo) {
  float v[8] = {p0.x, p0.y, p0.z, p0.w, p1.x, p1.y, p1.z, p1.w};
#pragma unroll
  for (int i = 0; i < 8; ++i) {
    unsigned short h = f2bf(v[i]);
    hi[i] = h;
    lo[i] = f2bf(v[i] - bf2f(h));
  }
}

// Kernel 0: W_ih fp32 -> bf16 hi/lo, padded to 272 rows of 64.
__global__ void conv_w(const float* __restrict__ W_ih,
                       unsigned short* __restrict__ hi,
                       unsigned short* __restrict__ lo) {
  int i = blockIdx.x * 256 + threadIdx.x;
  if (i >= GP * DD) return;
  int n = i >> 6;
  float w = (n < GG) ? W_ih[i] : 0.0f;
  unsigned short h = f2bf(w);
  hi[i] = h;
  lo[i] = f2bf(w - bf2f(h));
}

// Main: one block per batch element. 5 waves.
// Per 16-step subchunk: waves 0-3 MFMA x-projection (hi/lo split bf16) into
// LDS tr[tc][g]; then 16 recurrent steps with W_hh rows register-resident and
// h broadcast via v_readlane (VALU-only, no DS-pipe serialization).
// Wave 4 double-buffers the next x tile global->LDS during the steps.
__global__ __launch_bounds__(320, 3) void lstm_fused(
    const float* __restrict__ x,      // [B,T,D]
    const float* __restrict__ W_hh,   // [264,66]
    const float* __restrict__ b_ih,   // [264]
    const float* __restrict__ b_hh,   // [264]
    const unsigned short* __restrict__ WbHi,  // [272,64] bf16
    const unsigned short* __restrict__ WbLo,  // [272,64] bf16
    float* __restrict__ hT)           // [66,512]
{
  __shared__ __align__(16) float tr[16 * GP];        // [tc][g] x_proj tile
  __shared__ __align__(16) float xstage[2][16 * XSS]; // x rows, padded stride
  __shared__ __align__(16) float h_lds[68];
  __shared__ __align__(16) float sact[GG];

  const int tid = threadIdx.x;
  const int b = blockIdx.x;
  const int l = tid & 63;
  const int w = tid >> 6;
  const bool g_act = (tid < GG);
  const bool mm = (tid < 256);
  const bool w4 = (w == 4);
  const int mlane = l & 15;
  const int quad = l >> 4;

  // Recurrent weights: load UNCONDITIONALLY (clamped row) so the compiler
  // promotes the array to VGPRs (R1's conditional load demoted to scratch).
  float whh[HH];
  {
    int row = (tid < GG) ? tid : (GG - 1);
    const float* p = W_hh + row * HH;
#pragma unroll
    for (int j = 0; j < HH; ++j) whh[j] = p[j];
  }
  const bool istanh = (tid >= 2 * HH && tid < 3 * HH);

  // bias per mfma output column (folded into x_proj accumulator init)
  float biasCol[5];
#pragma unroll
  for (int ti = 0; ti < 5; ++ti) {
    int tau = w + 4 * ti;
    int g = tau * 16 + mlane;
    biasCol[ti] = (mm && tau < NTILE && g < GG) ? (b_ih[g] + b_hh[g]) : 0.0f;
  }

  // prologue: h0 = 0; stage x rows 0..15 into buffer 0
  if (tid < 68) h_lds[tid] = 0.0f;
  if (w4) {
    const int r = l >> 2, cq = l & 3;
    const float* src = x + ((size_t)b * TT + r) * DD + cq * 16;
    float4 v0 = *(const float4*)(src + 0);
    float4 v1 = *(const float4*)(src + 4);
    float4 v2 = *(const float4*)(src + 8);
    float4 v3 = *(const float4*)(src + 12);
    float* dst = &xstage[0][r * XSS + cq * 16];
    *(float4*)(dst + 0) = v0; *(float4*)(dst + 4) = v1;
    *(float4*)(dst + 8) = v2; *(float4*)(dst + 12) = v3;
  }
  float c = 0.0f, h = 0.0f;
  __syncthreads();

  for (int sc = 0; sc < NSUB; ++sc) {
    // ---- x-projection for steps t = sc*16 .. sc*16+15 ----
    if (mm) {
      const float* xs = &xstage[sc & 1][0];
      float4 a00 = *(const float4*)&xs[mlane * XSS + quad * 8];
      float4 a01 = *(const float4*)&xs[mlane * XSS + quad * 8 + 4];
      float4 a10 = *(const float4*)&xs[mlane * XSS + 32 + quad * 8];
      float4 a11 = *(const float4*)&xs[mlane * XSS + 32 + quad * 8 + 4];
      us8_t ah0, al0, ah1, al1;
      pack_hilo(a00, a01, ah0, al0);
      pack_hilo(a10, a11, ah1, al1);
#pragma unroll
      for (int ti = 0; ti < 5; ++ti) {
        int tau = w + 4 * ti;
        if (tau < NTILE) {
          int n = tau * 16 + mlane;
          const us8_t* bh = (const us8_t*)(WbHi + n * DD + quad * 8);
          const us8_t* bl = (const us8_t*)(WbLo + n * DD + quad * 8);
          us8_t bh0 = bh[0], bh1 = bh[4];  // +32 elements
          us8_t bl0 = bl[0], bl1 = bl[4];
          f4_t acc = {biasCol[ti], biasCol[ti], biasCol[ti], biasCol[ti]};
          acc = __builtin_amdgcn_mfma_f32_16x16x32_bf16(as_bf8(ah0), as_bf8(bh0), acc, 0, 0, 0);
          acc = __builtin_amdgcn_mfma_f32_16x16x32_bf16(as_bf8(ah1), as_bf8(bh1), acc, 0, 0, 0);
          acc = __builtin_amdgcn_mfma_f32_16x16x32_bf16(as_bf8(al0), as_bf8(bh0), acc, 0, 0, 0);
          acc = __builtin_amdgcn_mfma_f32_16x16x32_bf16(as_bf8(al1), as_bf8(bh1), acc, 0, 0, 0);
          acc = __builtin_amdgcn_mfma_f32_16x16x32_bf16(as_bf8(ah0), as_bf8(bl0), acc, 0, 0, 0);
          acc = __builtin_amdgcn_mfma_f32_16x16x32_bf16(as_bf8(ah1), as_bf8(bl1), acc, 0, 0, 0);
          int g = tau * 16 + mlane;
#pragma unroll
          for (int r = 0; r < 4; ++r) tr[(quad * 4 + r) * GP + g] = acc[r];
        }
      }
    }
    __syncthreads();  // tr ready

    const int scn = sc + 1;
    float4 pf0, pf1, pf2, pf3;
    if (w4 && scn < NSUB) {  // prefetch next x tile (latency hidden by steps)
      const int r = l >> 2, cq = l & 3;
      const float* src = x + ((size_t)b * TT + scn * 16 + r) * DD + cq * 16;
      pf0 = *(const float4*)(src + 0);
      pf1 = *(const float4*)(src + 4);
      pf2 = *(const float4*)(src + 8);
      pf3 = *(const float4*)(src + 12);
    }

    for (int s = 0; s < 16; ++s) {
      // h broadcast chunk: lane L holds h[4L..4L+3] (L=0..15). Load at FULL
      // exec and pin (readlane reads physical lanes; wave 4 has inactive
      // gate lanes, so the load must not sink under the divergent branch).
      float4 hv = *(const float4*)&h_lds[(l & 15) * 4];
      asm volatile("" : "+v"(hv.x), "+v"(hv.y), "+v"(hv.z), "+v"(hv.w));
      if (g_act) {
        float4 hx = *(const float4*)&h_lds[64];  // uniform broadcast h[64..67]
        float accv = tr[s * GP + tid];
#pragma unroll
        for (int j = 0; j < 64; ++j) {
          float hc = (j & 3) == 0 ? hv.x : ((j & 3) == 1 ? hv.y : ((j & 3) == 2 ? hv.z : hv.w));
          float hj = __builtin_bit_cast(
              float, __builtin_amdgcn_readlane(__builtin_bit_cast(int, hc), j >> 2));
          accv = fmaf(hj, whh[j], accv);
        }
        accv = fmaf(hx.x, whh[64], accv);
        accv = fmaf(hx.y, whh[65], accv);
        sact[tid] = istanh ? fast_tanh(accv) : fast_sigmoid(accv);
      }
      if (w4 && s == 8 && scn < NSUB) {  // commit prefetched tile
        const int r = l >> 2, cq = l & 3;
        float* dst = &xstage[scn & 1][r * XSS + cq * 16];
        *(float4*)(dst + 0) = pf0; *(float4*)(dst + 4) = pf1;
        *(float4*)(dst + 8) = pf2; *(float4*)(dst + 12) = pf3;
      }
      __syncthreads();  // gates ready
      if (tid < HH) {
        float iv = sact[tid];
        float fv = sact[HH + tid];
        float gv = sact[2 * HH + tid];
        float ov = sact[3 * HH + tid];
        c = fmaf(fv, c, iv * gv);
        h = ov * fast_tanh(c);
        h_lds[tid] = h;
      }
      __syncthreads();  // h ready
    }
  }
  if (tid < HH) hT[tid * BB + b] = h;
}

// BN batch-stats folded into final linear. Single block.
__global__ __launch_bounds__(512) void bn_fc(
    const float* __restrict__ hT, const float* __restrict__ gamma,
    const float* __restrict__ beta, const float* __restrict__ fc_w,
    const float* __restrict__ fc_b, float* __restrict__ out) {
  __shared__ float w2[HH];
  __shared__ float s2[HH];
  const int tid = threadIdx.x;
  const int wv = tid >> 6;
  const int lane = tid & 63;

  for (int j = wv; j < HH; j += 8) {
    const float* p = hT + j * BB;
    float s = 0.0f, ss = 0.0f;
#pragma unroll
    for (int m = 0; m < 8; ++m) {
      float v = p[lane + (m << 6)];
      s += v;
      ss = fmaf(v, v, ss);
    }
#pragma unroll
    for (int d = 32; d >= 1; d >>= 1) {
      s += __shfl_xor(s, d);
      ss += __shfl_xor(ss, d);
    }
    if (lane == 0) {
      float mean = s * (1.0f / BB);
      float var = ss * (1.0f / BB) - mean * mean;
      float scale = gamma[j] * rsqrtf(var + 1e-5f);
      float shift = beta[j] - mean * scale;
      float fw = fc_w[j];
      w2[j] = scale * fw;
      s2[j] = shift * fw;
    }
  }
  __syncthreads();

  float acc = 0.0f;
#pragma unroll
  for (int j = 0; j < HH; ++j) acc = fmaf(hT[j * BB + tid], w2[j], acc);
  float cst = fc_b[0];
#pragma unroll
  for (int j = 0; j < HH; ++j) cst += s2[j];
  out[tid] = acc + cst;
}

extern "C" void kernel_launch(void* const* d_in, const int* in_sizes, int n_in,
                              void* d_out, int out_size, void* d_ws, size_t ws_size,
                              hipStream_t stream) {
  const float* x     = (const float*)d_in[0];
  const float* W_ih  = (const float*)d_in[1];
  const float* W_hh  = (const float*)d_in[2];
  const float* b_ih  = (const float*)d_in[3];
  const float* b_hh  = (const float*)d_in[4];
  const float* gamma = (const float*)d_in[5];
  const float* beta  = (const float*)d_in[6];
  const float* fc_w  = (const float*)d_in[7];
  const float* fc_b  = (const float*)d_in[8];
  float* out = (float*)d_out;

  unsigned short* wbhi = (unsigned short*)d_ws;                       // 34816 B
  unsigned short* wblo = (unsigned short*)((char*)d_ws + 34816);      // 34816 B
  float* hT            = (float*)((char*)d_ws + 69632);               // 135168 B

  conv_w<<<68, 256, 0, stream>>>(W_ih, wbhi, wblo);
  lstm_fused<<<BB, 320, 0, stream>>>(x, W_hh, b_ih, b_hh, wbhi, wblo, hT);
  bn_fc<<<1, 512, 0, stream>>>(hT, gamma, beta, fc_w, fc_b, out);
}

// Round 4
// 4085.268 us; speedup vs baseline: 1.2233x; 1.0229x over previous
//
#include <hip/hip_runtime.h>
#include <math.h>

#define BB 512   // batch
#define TT 2048  // timesteps
#define DD 64    // input dim
#define HH 66    // hidden
#define GG 264   // 4*HH gates
#define GP 272   // padded gates (17 mfma n-tiles of 16)
#define NTILE 17
#define XSS 68   // xstage row stride (floats)
#define NSUB 128 // 128 subchunks x 16 steps = 2048

typedef __attribute__((ext_vector_type(8))) __bf16 bf8_t;
typedef __attribute__((ext_vector_type(8))) unsigned short us8_t;
typedef __attribute__((ext_vector_type(4))) float f4_t;

__device__ __forceinline__ float fast_sigmoid(float x) {
  float e = __expf(-x);
  return __fdividef(1.0f, 1.0f + e);
}
__device__ __forceinline__ float fast_tanh(float x) {
  float e = __expf(2.0f * x);
  return 1.0f - __fdividef(2.0f, e + 1.0f);
}
__device__ __forceinline__ unsigned short f2bf(float f) {
  unsigned u = __builtin_bit_cast(unsigned, f);
  unsigned r = (u + 0x7fffu + ((u >> 16) & 1u)) >> 16;
  return (unsigned short)r;
}
__device__ __forceinline__ float bf2f(unsigned short h) {
  unsigned u = ((unsigned)h) << 16;
  return __builtin_bit_cast(float, u);
}
static __device__ __forceinline__ bf8_t as_bf8(us8_t u) {
  union { us8_t u; bf8_t b; } v; v.u = u; return v.b;
}
__device__ __forceinline__ void pack_hilo(float4 p0, float4 p1, us8_t& hi, us8_t& lo) {
  float v[8] = {p0.x, p0.y, p0.z, p0.w, p1.x, p1.y, p1.z, p1.w};
#pragma unroll
  for (int i = 0; i < 8; ++i) {
    unsigned short h = f2bf(v[i]);
    hi[i] = h;
    lo[i] = f2bf(v[i] - bf2f(h));
  }
}

// 66 named scalar registers for the W_hh row: SSA values, cannot be demoted
// to scratch (R1/R2: whh[66] array failed SROA -> VGPR_Count=84 -> scratch
// reloads every step were the dominant stall). Prefix wr to avoid colliding
// with local identifiers (R3 compile failure: w4).
#define RL64(X) \
  X(0) X(1) X(2) X(3) X(4) X(5) X(6) X(7) X(8) X(9) \
  X(10) X(11) X(12) X(13) X(14) X(15) X(16) X(17) X(18) X(19) \
  X(20) X(21) X(22) X(23) X(24) X(25) X(26) X(27) X(28) X(29) \
  X(30) X(31) X(32) X(33) X(34) X(35) X(36) X(37) X(38) X(39) \
  X(40) X(41) X(42) X(43) X(44) X(45) X(46) X(47) X(48) X(49) \
  X(50) X(51) X(52) X(53) X(54) X(55) X(56) X(57) X(58) X(59) \
  X(60) X(61) X(62) X(63)

#define DECLW(i) float wr##i;
#define LOADW(i) wr##i = p[(i)];
// h[i] broadcast: component (i&3) of lane (i>>2)'s float4 == h_lds[i].
// Constant-folded select + readlane; acc[i&3] rotates deps at distance 4.
#define HSEL(i) (((i) & 3) == 0 ? hv.x : ((i) & 3) == 1 ? hv.y : ((i) & 3) == 2 ? hv.z : hv.w)
#define FMAW(i)                                                               \
  {                                                                           \
    float hj = __builtin_bit_cast(                                            \
        float, __builtin_amdgcn_readlane(__builtin_bit_cast(int, HSEL(i)),    \
                                         (i) >> 2));                          \
    acc[(i) & 3] = fmaf(hj, wr##i, acc[(i) & 3]);                             \
  }

// Kernel 0: W_ih fp32 -> bf16 hi/lo, padded to 272 rows of 64.
__global__ void conv_w(const float* __restrict__ W_ih,
                       unsigned short* __restrict__ hi,
                       unsigned short* __restrict__ lo) {
  int i = blockIdx.x * 256 + threadIdx.x;
  if (i >= GP * DD) return;
  int n = i >> 6;
  float w = (n < GG) ? W_ih[i] : 0.0f;
  unsigned short h = f2bf(w);
  hi[i] = h;
  lo[i] = f2bf(w - bf2f(h));
}

__global__ __launch_bounds__(320, 2) void lstm_fused(
    const float* __restrict__ x,      // [B,T,D]
    const float* __restrict__ W_hh,   // [264,66]
    const float* __restrict__ b_ih,   // [264]
    const float* __restrict__ b_hh,   // [264]
    const unsigned short* __restrict__ WbHi,  // [272,64] bf16
    const unsigned short* __restrict__ WbLo,  // [272,64] bf16
    float* __restrict__ hT)           // [66,512]
{
  __shared__ __align__(16) float tr[16 * GP];         // [tc][g] x_proj tile
  __shared__ __align__(16) float xstage[2][16 * XSS]; // x rows
  __shared__ __align__(16) float h_lds[68];
  __shared__ __align__(16) float sact[GG];

  const int tid = threadIdx.x;
  const int b = blockIdx.x;
  const int l = tid & 63;
  const int w = tid >> 6;
  const bool gate = (tid < GG);
  const bool mm = (tid < 256);
  const bool isW4 = (w == 4);
  const int mlane = l & 15;
  const int quad = l >> 4;

  // W_hh row in 66 named scalars (clamped row for non-gate threads).
  RL64(DECLW) float wr64, wr65;
  {
    const int row = gate ? tid : (GG - 1);
    const float* p = W_hh + row * HH;
    RL64(LOADW) wr64 = p[64]; wr65 = p[65];
  }
  const bool istanh = (tid >= 2 * HH && tid < 3 * HH);

  float biasCol[5];
#pragma unroll
  for (int ti = 0; ti < 5; ++ti) {
    int tau = w + 4 * ti;
    int g = tau * 16 + mlane;
    biasCol[ti] = (mm && tau < NTILE && g < GG) ? (b_ih[g] + b_hh[g]) : 0.0f;
  }

  if (tid < 68) h_lds[tid] = 0.0f;
  if (isW4) {
    const int r = l >> 2, cq = l & 3;
    const float* src = x + ((size_t)b * TT + r) * DD + cq * 16;
    float4 v0 = *(const float4*)(src + 0);
    float4 v1 = *(const float4*)(src + 4);
    float4 v2 = *(const float4*)(src + 8);
    float4 v3 = *(const float4*)(src + 12);
    float* dst = &xstage[0][r * XSS + cq * 16];
    *(float4*)(dst + 0) = v0; *(float4*)(dst + 4) = v1;
    *(float4*)(dst + 8) = v2; *(float4*)(dst + 12) = v3;
  }
  float c = 0.0f, h = 0.0f;
  __syncthreads();

  for (int sc = 0; sc < NSUB; ++sc) {
    // ---- x-projection (bf16 hi/lo MFMA) for the next 16 steps ----
    if (mm) {
      const float* xs = &xstage[sc & 1][0];
      float4 a00 = *(const float4*)&xs[mlane * XSS + quad * 8];
      float4 a01 = *(const float4*)&xs[mlane * XSS + quad * 8 + 4];
      float4 a10 = *(const float4*)&xs[mlane * XSS + 32 + quad * 8];
      float4 a11 = *(const float4*)&xs[mlane * XSS + 32 + quad * 8 + 4];
      us8_t ah0, al0, ah1, al1;
      pack_hilo(a00, a01, ah0, al0);
      pack_hilo(a10, a11, ah1, al1);
#pragma unroll
      for (int ti = 0; ti < 5; ++ti) {
        int tau = w + 4 * ti;
        if (tau < NTILE) {
          int n = tau * 16 + mlane;
          const us8_t* bh = (const us8_t*)(WbHi + n * DD + quad * 8);
          const us8_t* bl = (const us8_t*)(WbLo + n * DD + quad * 8);
          us8_t bh0 = bh[0], bh1 = bh[4];
          us8_t bl0 = bl[0], bl1 = bl[4];
          f4_t acc = {biasCol[ti], biasCol[ti], biasCol[ti], biasCol[ti]};
          acc = __builtin_amdgcn_mfma_f32_16x16x32_bf16(as_bf8(ah0), as_bf8(bh0), acc, 0, 0, 0);
          acc = __builtin_amdgcn_mfma_f32_16x16x32_bf16(as_bf8(ah1), as_bf8(bh1), acc, 0, 0, 0);
          acc = __builtin_amdgcn_mfma_f32_16x16x32_bf16(as_bf8(al0), as_bf8(bh0), acc, 0, 0, 0);
          acc = __builtin_amdgcn_mfma_f32_16x16x32_bf16(as_bf8(al1), as_bf8(bh1), acc, 0, 0, 0);
          acc = __builtin_amdgcn_mfma_f32_16x16x32_bf16(as_bf8(ah0), as_bf8(bl0), acc, 0, 0, 0);
          acc = __builtin_amdgcn_mfma_f32_16x16x32_bf16(as_bf8(ah1), as_bf8(bl1), acc, 0, 0, 0);
          int g = tau * 16 + mlane;
#pragma unroll
          for (int r = 0; r < 4; ++r) tr[(quad * 4 + r) * GP + g] = acc[r];
        }
      }
    }
    __syncthreads();  // tr ready

    const int scn = sc + 1;
    float4 pf0, pf1, pf2, pf3;
    if (isW4 && scn < NSUB) {
      const int r = l >> 2, cq = l & 3;
      const float* src = x + ((size_t)b * TT + scn * 16 + r) * DD + cq * 16;
      pf0 = *(const float4*)(src + 0);
      pf1 = *(const float4*)(src + 4);
      pf2 = *(const float4*)(src + 8);
      pf3 = *(const float4*)(src + 12);
    }

    for (int s = 0; s < 16; ++s) {
      // Load at FULL exec and pin: readlane reads physical lanes, so even
      // wave 4's non-gate lanes must hold valid hv.
      float4 hv = *(const float4*)&h_lds[(l & 15) * 4];
      asm volatile("" : "+v"(hv.x), "+v"(hv.y), "+v"(hv.z), "+v"(hv.w));
      if (gate) {
        float h64v = h_lds[64];   // uniform -> broadcast reads
        float h65v = h_lds[65];
        float acc[4];
        acc[0] = tr[s * GP + tid];  // x_proj + bias
        acc[1] = 0.0f; acc[2] = 0.0f; acc[3] = 0.0f;
        RL64(FMAW)
        acc[0] = fmaf(h64v, wr64, acc[0]);
        acc[1] = fmaf(h65v, wr65, acc[1]);
        float pre = (acc[0] + acc[1]) + (acc[2] + acc[3]);
        sact[tid] = istanh ? fast_tanh(pre) : fast_sigmoid(pre);
      }
      if (isW4 && s == 8 && scn < NSUB) {
        const int r = l >> 2, cq = l & 3;
        float* dst = &xstage[scn & 1][r * XSS + cq * 16];
        *(float4*)(dst + 0) = pf0; *(float4*)(dst + 4) = pf1;
        *(float4*)(dst + 8) = pf2; *(float4*)(dst + 12) = pf3;
      }
      __syncthreads();  // gates ready
      if (tid < HH) {
        float iv = sact[tid];
        float fv = sact[HH + tid];
        float gv = sact[2 * HH + tid];
        float ov = sact[3 * HH + tid];
        c = fmaf(fv, c, iv * gv);
        h = ov * fast_tanh(c);
        h_lds[tid] = h;
      }
      __syncthreads();  // h ready
    }
  }
  if (tid < HH) hT[tid * BB + b] = h;
}

// BN batch-stats folded into final linear. Single block.
__global__ __launch_bounds__(512) void bn_fc(
    const float* __restrict__ hT, const float* __restrict__ gamma,
    const float* __restrict__ beta, const float* __restrict__ fc_w,
    const float* __restrict__ fc_b, float* __restrict__ out) {
  __shared__ float w2[HH];
  __shared__ float s2[HH];
  const int tid = threadIdx.x;
  const int wv = tid >> 6;
  const int lane = tid & 63;

  for (int j = wv; j < HH; j += 8) {
    const float* p = hT + j * BB;
    float s = 0.0f, ss = 0.0f;
#pragma unroll
    for (int m = 0; m < 8; ++m) {
      float v = p[lane + (m << 6)];
      s += v;
      ss = fmaf(v, v, ss);
    }
#pragma unroll
    for (int d = 32; d >= 1; d >>= 1) {
      s += __shfl_xor(s, d);
      ss += __shfl_xor(ss, d);
    }
    if (lane == 0) {
      float mean = s * (1.0f / BB);
      float var = ss * (1.0f / BB) - mean * mean;
      float scale = gamma[j] * rsqrtf(var + 1e-5f);
      float shift = beta[j] - mean * scale;
      float fw = fc_w[j];
      w2[j] = scale * fw;
      s2[j] = shift * fw;
    }
  }
  __syncthreads();

  float acc = 0.0f;
#pragma unroll
  for (int j = 0; j < HH; ++j) acc = fmaf(hT[j * BB + tid], w2[j], acc);
  float cst = fc_b[0];
#pragma unroll
  for (int j = 0; j < HH; ++j) cst += s2[j];
  out[tid] = acc + cst;
}

extern "C" void kernel_launch(void* const* d_in, const int* in_sizes, int n_in,
                              void* d_out, int out_size, void* d_ws, size_t ws_size,
                              hipStream_t stream) {
  const float* x     = (const float*)d_in[0];
  const float* W_ih  = (const float*)d_in[1];
  const float* W_hh  = (const float*)d_in[2];
  const float* b_ih  = (const float*)d_in[3];
  const float* b_hh  = (const float*)d_in[4];
  const float* gamma = (const float*)d_in[5];
  const float* beta  = (const float*)d_in[6];
  const float* fc_w  = (const float*)d_in[7];
  const float* fc_b  = (const float*)d_in[8];
  float* out = (float*)d_out;

  unsigned short* wbhi = (unsigned short*)d_ws;                  // 34816 B
  unsigned short* wblo = (unsigned short*)((char*)d_ws + 34816); // 34816 B
  float* hT            = (float*)((char*)d_ws + 69632);          // 135168 B

  conv_w<<<68, 256, 0, stream>>>(W_ih, wbhi, wblo);
  lstm_fused<<<BB, 320, 0, stream>>>(x, W_hh, b_ih, b_hh, wbhi, wblo, hT);
  bn_fc<<<1, 512, 0, stream>>>(hT, gamma, beta, fc_w, fc_b, out);
}